// Round 1
// baseline (419.335 us; speedup 1.0000x reference)
//
#include <hip/hip_runtime.h>
#include <cstdint>

using u16 = unsigned short;
using u32 = unsigned int;

typedef __attribute__((ext_vector_type(8))) short short8v;   // 8 x bf16 (as raw u16)
typedef __attribute__((ext_vector_type(4))) float f32x4;

#define MFMA_BF16(a, b, c) __builtin_amdgcn_mfma_f32_16x16x32_bf16((a), (b), (c), 0, 0, 0)

__device__ __forceinline__ u16 f2bf(float f) {
  u32 u = __float_as_uint(f);
  u += 0x7fffu + ((u >> 16) & 1u);   // RNE
  return (u16)(u >> 16);
}
__device__ __forceinline__ float bf2f(u32 s) { return __uint_as_float(s << 16); }

// global -> LDS direct copy, 16B per lane. LDS dest must be wave-uniform base;
// HW writes base + lane*16. Integer casts avoid addrspacecast issues:
// low 32 bits of a flat LDS address are the LDS offset on gfx9xx.
__device__ __forceinline__ void g2l16(const u16* g, const u16* l) {
  __builtin_amdgcn_global_load_lds(
      (const __attribute__((address_space(1))) u32*)(uintptr_t)g,
      (__attribute__((address_space(3))) u32*)(u32)(uintptr_t)l, 16, 0, 0);
}

// ---------------- fp32 -> bf16 conversion (vectorized) ----------------
__global__ __launch_bounds__(256) void cvt_f32_bf16(const float* __restrict__ src,
                                                    u16* __restrict__ dst, int n4) {
  int i = blockIdx.x * blockDim.x + threadIdx.x;
  if (i >= n4) return;
  const float4 v = ((const float4*)src)[i];
  ushort4 o;
  o.x = f2bf(v.x); o.y = f2bf(v.y); o.z = f2bf(v.z); o.w = f2bf(v.w);
  ((ushort4*)dst)[i] = o;
}

// ---------------- NT GEMM: C[M][N] = A[M][K] * B[N][K]^T, bf16 in, K=1024 ----
// 128x128 tile, BK=64, 4 waves in 2x2, global_load_lds staging (m97 structure).
template <bool OUT_BF16>
__global__ __launch_bounds__(256) void gemm_nt(const u16* __restrict__ A,
                                               const u16* __restrict__ B,
                                               void* __restrict__ C, int ldc) {
  constexpr int K = 1024;
  __shared__ u16 As[128 * 64];
  __shared__ u16 Bs[128 * 64];
  const int tid = threadIdx.x;
  const int lane = tid & 63, wave = tid >> 6;
  const int lr = lane & 15, lg = lane >> 4;
  const int bm = blockIdx.y * 128, bn = blockIdx.x * 128;
  const int wm = (wave >> 1) * 64, wn = (wave & 1) * 64;
  f32x4 acc[4][4] = {};
  for (int k0 = 0; k0 < K; k0 += 64) {
#pragma unroll
    for (int it = 0; it < 4; ++it) {
      const int ci = it * 4 + wave;              // 16 chunks of 1 KB per tile
      const int li = ci * 512 + lane * 8;        // ushort linear index
      const int row = li >> 6, col = li & 63;
      g2l16(A + (size_t)(bm + row) * K + k0 + col, As + ci * 512);
      g2l16(B + (size_t)(bn + row) * K + k0 + col, Bs + ci * 512);
    }
    __syncthreads();   // drains vmcnt before barrier
#pragma unroll
    for (int kk = 0; kk < 2; ++kk) {
      short8v af[4], bf[4];
#pragma unroll
      for (int m = 0; m < 4; ++m)
        af[m] = *(const short8v*)&As[(wm + m * 16 + lr) * 64 + kk * 32 + lg * 8];
#pragma unroll
      for (int n = 0; n < 4; ++n)
        bf[n] = *(const short8v*)&Bs[(wn + n * 16 + lr) * 64 + kk * 32 + lg * 8];
#pragma unroll
      for (int m = 0; m < 4; ++m)
#pragma unroll
        for (int n = 0; n < 4; ++n)
          acc[m][n] = MFMA_BF16(af[m], bf[n], acc[m][n]);
    }
    __syncthreads();
  }
  // epilogue: C/D layout col = lane&15, row = (lane>>4)*4 + r
#pragma unroll
  for (int m = 0; m < 4; ++m)
#pragma unroll
    for (int n = 0; n < 4; ++n)
#pragma unroll
      for (int r = 0; r < 4; ++r) {
        const int row = bm + wm + m * 16 + lg * 4 + r;
        const int col = bn + wn + n * 16 + lr;
        if (OUT_BF16)
          ((u16*)C)[(size_t)row * ldc + col] = f2bf(acc[m][n][r]);
        else
          ((float*)C)[(size_t)row * ldc + col] = acc[m][n][r];
      }
}

// ---------------- RoPE in-place on QKV cols [0,2048) -----------------------
// one thread per (row, pair); pair = packed uint of (even,odd) bf16
__global__ __launch_bounds__(256) void rope_kernel(u32* __restrict__ QKVu,
                                                   const int* __restrict__ tpos) {
  const int t = blockIdx.x * 256 + threadIdx.x;   // 0 .. 8192*1024-1
  const int row = t >> 10, pp = t & 1023;
  const int col = (pp < 512) ? (pp * 2) : (1024 + (pp - 512) * 2);
  const size_t uidx = ((size_t)row * 3072 + col) >> 1;
  const u32 u = QKVu[uidx];
  const float e = bf2f(u & 0xffffu), o = bf2f(u >> 16);
  const int i = pp & 31;                          // pair index within head (dk=64)
  const float pos = (float)tpos[row & 2047];
  // inv_freq = 10000^(-i/32) = exp(-i * ln(10000)/32)
  const float ang = pos * __expf((float)i * -0.28782313662425574f);
  float sn, cs;
  sincosf(ang, &sn, &cs);
  const float ne = e * cs - o * sn;
  const float no = o * cs + e * sn;
  QKVu[uidx] = (u32)f2bf(ne) | ((u32)f2bf(no) << 16);
}

// ---------------- causal flash attention ----------------------------------
// block = (qt, h, b): 64 q-rows; 4 waves x 16 rows. dk = 64. K/V tiles 64x64.
__global__ __launch_bounds__(256) void attn_kernel(const u16* __restrict__ QKV,
                                                   u16* __restrict__ O) {
  const int qt = blockIdx.x, h = blockIdx.y, b = blockIdx.z;
  const int tid = threadIdx.x, lane = tid & 63, wave = tid >> 6;
  const int lr = lane & 15, lg = lane >> 4;
  __shared__ u16 Kt[64 * 72];     // K rows (padded +8 -> 2-way-free banks)
  __shared__ u16 Vt[64 * 72];     // V transposed: Vt[d][krow]
  __shared__ u16 Ps[4][16 * 72];  // per-wave P staging
  const size_t baserow = (size_t)b * 2048;
  const int ldq = 3072;

  // hoist Q fragments (wave's 16 rows x 64 dk) into registers
  short8v qf0, qf1;
  {
    const u16* qp = QKV + (baserow + qt * 64 + wave * 16 + lr) * ldq + h * 64 + lg * 8;
    qf0 = *(const short8v*)qp;
    qf1 = *(const short8v*)(qp + 32);
  }
  f32x4 oacc[4] = {};
  float m_run[4] = {-1e30f, -1e30f, -1e30f, -1e30f};
  float l_run[4] = {};

  for (int kt = 0; kt <= qt; ++kt) {
    {  // stage K (row-major) and V (transposed)
      const int r = tid >> 2, cb = (tid & 3) * 16;
      const u16* kp = QKV + (baserow + kt * 64 + r) * ldq + 1024 + h * 64 + cb;
      const u16* vp = kp + 1024;
      *(short8v*)&Kt[r * 72 + cb] = *(const short8v*)kp;
      *(short8v*)&Kt[r * 72 + cb + 8] = *(const short8v*)(kp + 8);
      u16 vtmp[16];
      *(short8v*)&vtmp[0] = *(const short8v*)vp;
      *(short8v*)&vtmp[8] = *(const short8v*)(vp + 8);
#pragma unroll
      for (int j = 0; j < 16; ++j) Vt[(cb + j) * 72 + r] = vtmp[j];
    }
    __syncthreads();

    // S = Q K^T for this wave's 16 rows x 64 k-cols
    f32x4 sacc[4] = {};
#pragma unroll
    for (int c = 0; c < 4; ++c) {
      const short8v kf0 = *(const short8v*)&Kt[(c * 16 + lr) * 72 + lg * 8];
      const short8v kf1 = *(const short8v*)&Kt[(c * 16 + lr) * 72 + 32 + lg * 8];
      sacc[c] = MFMA_BF16(qf0, kf0, sacc[c]);
      sacc[c] = MFMA_BF16(qf1, kf1, sacc[c]);
    }

    const int qbase = qt * 64 + wave * 16 + lg * 4;  // + r
    const int kbase = kt * 64 + lr;                  // + c*16
    const bool diag = (kt == qt);
    float p[4][4];
    float xm[4] = {-1e30f, -1e30f, -1e30f, -1e30f};
#pragma unroll
    for (int c = 0; c < 4; ++c)
#pragma unroll
      for (int r = 0; r < 4; ++r) {
        float v = sacc[c][r] * 0.125f;  // 1/sqrt(64)
        if (diag && (kbase + c * 16 > qbase + r)) v = -1e30f;
        p[c][r] = v;
        xm[r] = fmaxf(xm[r], v);
      }
    // row max across the 16-lane group
#pragma unroll
    for (int mk = 1; mk <= 8; mk <<= 1)
#pragma unroll
      for (int r = 0; r < 4; ++r) xm[r] = fmaxf(xm[r], __shfl_xor(xm[r], mk));
    float alpha[4];
#pragma unroll
    for (int r = 0; r < 4; ++r) {
      const float mn = fmaxf(m_run[r], xm[r]);
      alpha[r] = __expf(m_run[r] - mn);
      m_run[r] = mn;
    }
    float rs[4] = {};
#pragma unroll
    for (int c = 0; c < 4; ++c)
#pragma unroll
      for (int r = 0; r < 4; ++r) {
        const float e = __expf(p[c][r] - m_run[r]);
        p[c][r] = e;
        rs[r] += e;
      }
#pragma unroll
    for (int mk = 1; mk <= 8; mk <<= 1)
#pragma unroll
      for (int r = 0; r < 4; ++r) rs[r] += __shfl_xor(rs[r], mk);
#pragma unroll
    for (int r = 0; r < 4; ++r) l_run[r] = l_run[r] * alpha[r] + rs[r];
#pragma unroll
    for (int n = 0; n < 4; ++n) {
      f32x4 tmp = oacc[n];
      tmp[0] *= alpha[0]; tmp[1] *= alpha[1]; tmp[2] *= alpha[2]; tmp[3] *= alpha[3];
      oacc[n] = tmp;
    }
    // P -> wave-private LDS (relayout accum->A-frag), then O += P V
    u16* P = &Ps[wave][0];
#pragma unroll
    for (int c = 0; c < 4; ++c)
#pragma unroll
      for (int r = 0; r < 4; ++r)
        P[(lg * 4 + r) * 72 + c * 16 + lr] = f2bf(p[c][r]);
    const short8v pa0 = *(const short8v*)&P[lr * 72 + lg * 8];
    const short8v pa1 = *(const short8v*)&P[lr * 72 + 32 + lg * 8];
#pragma unroll
    for (int n = 0; n < 4; ++n) {
      const short8v vf0 = *(const short8v*)&Vt[(n * 16 + lr) * 72 + lg * 8];
      const short8v vf1 = *(const short8v*)&Vt[(n * 16 + lr) * 72 + 32 + lg * 8];
      oacc[n] = MFMA_BF16(pa0, vf0, oacc[n]);
      oacc[n] = MFMA_BF16(pa1, vf1, oacc[n]);
    }
    __syncthreads();
  }

#pragma unroll
  for (int n = 0; n < 4; ++n)
#pragma unroll
    for (int r = 0; r < 4; ++r) {
      const int qpos = qt * 64 + wave * 16 + lg * 4 + r;
      O[(baserow + qpos) * 1024 + h * 64 + n * 16 + lr] = f2bf(oacc[n][r] / l_run[r]);
    }
}

// ---------------------------------------------------------------------------
extern "C" void kernel_launch(void* const* d_in, const int* in_sizes, int n_in,
                              void* d_out, int out_size, void* d_ws, size_t ws_size,
                              hipStream_t stream) {
  (void)in_sizes; (void)n_in; (void)out_size; (void)ws_size;
  const float* x   = (const float*)d_in[0];
  const int* tpos  = (const int*)d_in[1];
  const float* Wq  = (const float*)d_in[2];
  const float* Wk  = (const float*)d_in[3];
  const float* Wv  = (const float*)d_in[4];
  const float* Wo  = (const float*)d_in[5];
  float* out = (float*)d_out;

  // workspace layout (72 MB total)
  char* ws = (char*)d_ws;
  u16* xb   = (u16*)(ws);                         // 16 MB; reused as attn_out
  u16* Wqkv = (u16*)(ws + (size_t)(16 << 20));    // 6 MB  ([3072][1024])
  u16* Wob  = (u16*)(ws + (size_t)(22 << 20));    // 2 MB
  u16* QKV  = (u16*)(ws + (size_t)(24 << 20));    // 48 MB ([8192][3072])

  // fp32 -> bf16
  cvt_f32_bf16<<<8192, 256, 0, stream>>>(x, xb, 8388608 / 4);
  cvt_f32_bf16<<<1024, 256, 0, stream>>>(Wq, Wqkv, 1048576 / 4);
  cvt_f32_bf16<<<1024, 256, 0, stream>>>(Wk, Wqkv + 1048576, 1048576 / 4);
  cvt_f32_bf16<<<1024, 256, 0, stream>>>(Wv, Wqkv + 2097152, 1048576 / 4);
  cvt_f32_bf16<<<1024, 256, 0, stream>>>(Wo, Wob, 1048576 / 4);

  // QKV = xb @ Wqkv^T   (M=8192, N=3072, K=1024)
  gemm_nt<true><<<dim3(24, 64), 256, 0, stream>>>(xb, Wqkv, QKV, 3072);

  // RoPE in place on Q and K columns
  rope_kernel<<<32768, 256, 0, stream>>>((u32*)QKV, tpos);

  // causal flash attention -> attn_out (reuses xb region)
  attn_kernel<<<dim3(32, 16, 4), 256, 0, stream>>>(QKV, xb);

  // out = attn_out @ Wo^T  (fp32 epilogue)
  gemm_nt<false><<<dim3(8, 64), 256, 0, stream>>>(xb, Wob, out, 1024);
}

// Round 2
// 278.842 us; speedup vs baseline: 1.5038x; 1.5038x over previous
//
#include <hip/hip_runtime.h>
#include <cstdint>

using u16 = unsigned short;
using u32 = unsigned int;

typedef __attribute__((ext_vector_type(8))) short short8v;   // 8 x bf16 (raw u16)
typedef __attribute__((ext_vector_type(4))) float f32x4;

#define MFMA_BF16(a, b, c) __builtin_amdgcn_mfma_f32_16x16x32_bf16((a), (b), (c), 0, 0, 0)

__device__ __forceinline__ u16 f2bf(float f) {
  u32 u = __float_as_uint(f);
  u += 0x7fffu + ((u >> 16) & 1u);   // RNE
  return (u16)(u >> 16);
}
__device__ __forceinline__ float bf2f(u32 s) { return __uint_as_float(s << 16); }

__device__ __forceinline__ void g2l16(const u16* g, const u16* l) {
  __builtin_amdgcn_global_load_lds(
      (const __attribute__((address_space(1))) u32*)(uintptr_t)g,
      (__attribute__((address_space(3))) u32*)(u32)(uintptr_t)l, 16, 0, 0);
}

// ---------------- fp32 -> bf16 conversion ----------------
__global__ __launch_bounds__(256) void cvt_f32_bf16(const float* __restrict__ src,
                                                    u16* __restrict__ dst, int n4) {
  int i = blockIdx.x * blockDim.x + threadIdx.x;
  if (i >= n4) return;
  const float4 v = ((const float4*)src)[i];
  ushort4 o;
  o.x = f2bf(v.x); o.y = f2bf(v.y); o.z = f2bf(v.z); o.w = f2bf(v.w);
  ((ushort4*)dst)[i] = o;
}

// ---------------- NT GEMM: C[M][N] = A[M][K] * B[N][K]^T, bf16 in, K=1024 ----
template <bool OUT_BF16>
__global__ __launch_bounds__(256) void gemm_nt(const u16* __restrict__ A,
                                               const u16* __restrict__ B,
                                               void* __restrict__ C, int ldc) {
  constexpr int K = 1024;
  __shared__ u16 As[128 * 64];
  __shared__ u16 Bs[128 * 64];
  const int tid = threadIdx.x;
  const int lane = tid & 63, wave = tid >> 6;
  const int lr = lane & 15, lg = lane >> 4;
  const int bm = blockIdx.y * 128, bn = blockIdx.x * 128;
  const int wm = (wave >> 1) * 64, wn = (wave & 1) * 64;
  f32x4 acc[4][4] = {};
  for (int k0 = 0; k0 < K; k0 += 64) {
#pragma unroll
    for (int it = 0; it < 4; ++it) {
      const int ci = it * 4 + wave;
      const int li = ci * 512 + lane * 8;
      const int row = li >> 6, col = li & 63;
      g2l16(A + (size_t)(bm + row) * K + k0 + col, As + ci * 512);
      g2l16(B + (size_t)(bn + row) * K + k0 + col, Bs + ci * 512);
    }
    __syncthreads();
#pragma unroll
    for (int kk = 0; kk < 2; ++kk) {
      short8v af[4], bf[4];
#pragma unroll
      for (int m = 0; m < 4; ++m)
        af[m] = *(const short8v*)&As[(wm + m * 16 + lr) * 64 + kk * 32 + lg * 8];
#pragma unroll
      for (int n = 0; n < 4; ++n)
        bf[n] = *(const short8v*)&Bs[(wn + n * 16 + lr) * 64 + kk * 32 + lg * 8];
#pragma unroll
      for (int m = 0; m < 4; ++m)
#pragma unroll
        for (int n = 0; n < 4; ++n)
          acc[m][n] = MFMA_BF16(af[m], bf[n], acc[m][n]);
    }
    __syncthreads();
  }
#pragma unroll
  for (int m = 0; m < 4; ++m)
#pragma unroll
    for (int n = 0; n < 4; ++n)
#pragma unroll
      for (int r = 0; r < 4; ++r) {
        const int row = bm + wm + m * 16 + lg * 4 + r;
        const int col = bn + wn + n * 16 + lr;
        if (OUT_BF16)
          ((u16*)C)[(size_t)row * ldc + col] = f2bf(acc[m][n][r]);
        else
          ((float*)C)[(size_t)row * ldc + col] = acc[m][n][r];
      }
}

// ---------------- RoPE in-place on QK buffer [8192][2048] -------------------
__global__ __launch_bounds__(256) void rope_kernel(u32* __restrict__ QKu,
                                                   const int* __restrict__ tpos) {
  const int t = blockIdx.x * 256 + threadIdx.x;   // 0 .. 8192*1024-1
  const int row = t >> 10, pp = t & 1023;
  const u32 u = QKu[t];
  const float e = bf2f(u & 0xffffu), o = bf2f(u >> 16);
  const int i = pp & 31;                          // pair index within head (dk=64)
  const float pos = (float)tpos[row & 2047];
  const float ang = pos * __expf((float)i * -0.28782313662425574f);
  float sn, cs;
  sincosf(ang, &sn, &cs);
  const float ne = e * cs - o * sn;
  const float no = o * cs + e * sn;
  QKu[t] = (u32)f2bf(ne) | ((u32)f2bf(no) << 16);
}

// ---------------- V transpose: Vtmp[8192][1024] -> Vt[b][h][d=64][s=2048] ---
__global__ __launch_bounds__(256) void transpose_v(const u16* __restrict__ Vtmp,
                                                   u16* __restrict__ Vt) {
  __shared__ u16 T[64][72];
  const int tid = threadIdx.x;
  const int st = blockIdx.x, h = blockIdx.y, b = blockIdx.z;
  {
    const int r = tid >> 2, cb = (tid & 3) * 16;
    const u16* src = Vtmp + ((size_t)(b * 2048 + st * 64 + r)) * 1024 + h * 64 + cb;
    *(short8v*)&T[r][cb] = *(const short8v*)src;
    *(short8v*)&T[r][cb + 8] = *(const short8v*)(src + 8);
  }
  __syncthreads();
  const int d = tid >> 2, sb = (tid & 3) * 16;
  u16 tmp[16];
#pragma unroll
  for (int j = 0; j < 16; ++j) tmp[j] = T[sb + j][d];
  u16* dst = Vt + ((size_t)((b * 16 + h) * 64 + d)) * 2048 + st * 64 + sb;
  *(short8v*)dst = *(const short8v*)&tmp[0];
  *(short8v*)(dst + 8) = *(const short8v*)&tmp[8];
}

// ---------------- causal flash attention ------------------------------------
// 512 blocks; each handles q-tiles {15-p, p} (128 rows each) for one (b,h).
// 4 waves x 32 q-rows. KVBLK=64. Double-buffered K/V LDS, register prefetch.
__global__ __launch_bounds__(256) void attn_kernel(const u16* __restrict__ QK,
                                                   const u16* __restrict__ Vt,
                                                   u16* __restrict__ O) {
  const int bid = blockIdx.x;
  const int hb = bid & 63, pr = bid >> 6;
  const int h = hb & 15, b = hb >> 4;
  const int tid = threadIdx.x, lane = tid & 63, wave = tid >> 6;
  const int lr = lane & 15, lg = lane >> 4;
  __shared__ u16 Kt[2][64 * 72];
  __shared__ u16 Vs[2][64 * 72];
  __shared__ u16 Ps[4][32 * 72];
  const size_t bbase = (size_t)b * 2048;
  const int r_st = tid >> 2, cb_st = (tid & 3) * 16;   // staging row/col
  const u16* Kbase = QK + (bbase + r_st) * 2048 + 1024 + h * 64 + cb_st;
  const u16* Vbase = Vt + ((size_t)(b * 16 + h) * 64 + r_st) * 2048 + cb_st;
  u16* Pw = &Ps[wave][0];

  const int qts[2] = {15 - pr, pr};
  for (int qi = 0; qi < 2; ++qi) {
    const int qt = qts[qi];
    const int nkt = 2 * qt + 2;
    // hoist Q fragments (wave's 32 rows x 64 dk)
    short8v qf[2][2];
#pragma unroll
    for (int m = 0; m < 2; ++m) {
      const u16* qp = QK + (bbase + qt * 128 + wave * 32 + m * 16 + lr) * 2048 + h * 64 + lg * 8;
      qf[m][0] = *(const short8v*)qp;
      qf[m][1] = *(const short8v*)(qp + 32);
    }
    f32x4 oacc[2][4] = {};
    float m_run[2][4], l_run[2][4];
#pragma unroll
    for (int m = 0; m < 2; ++m)
#pragma unroll
      for (int r = 0; r < 4; ++r) { m_run[m][r] = -1e30f; l_run[m][r] = 0.f; }

    // prefetch tile 0
    short8v ka, kb, va, vb;
    ka = *(const short8v*)(Kbase);
    kb = *(const short8v*)(Kbase + 8);
    va = *(const short8v*)(Vbase);
    vb = *(const short8v*)(Vbase + 8);
    __syncthreads();   // previous q-tile's consumers done with LDS
    int cur = 0;
    *(short8v*)&Kt[0][r_st * 72 + cb_st] = ka;
    *(short8v*)&Kt[0][r_st * 72 + cb_st + 8] = kb;
    *(short8v*)&Vs[0][r_st * 72 + cb_st] = va;
    *(short8v*)&Vs[0][r_st * 72 + cb_st + 8] = vb;

    for (int kt = 0; kt < nkt; ++kt) {
      __syncthreads();   // buf[cur] visible
      const bool more = (kt + 1 < nkt);
      if (more) {
        const u16* kp = Kbase + (size_t)(kt + 1) * 64 * 2048;
        const u16* vp = Vbase + (kt + 1) * 64;
        ka = *(const short8v*)kp;
        kb = *(const short8v*)(kp + 8);
        va = *(const short8v*)vp;
        vb = *(const short8v*)(vp + 8);
      }
      // ---- S = Q K^T (32 q-rows x 64 k) ----
      f32x4 sacc[2][4] = {};
#pragma unroll
      for (int c = 0; c < 4; ++c) {
        const short8v kf0 = *(const short8v*)&Kt[cur][(c * 16 + lr) * 72 + lg * 8];
        const short8v kf1 = *(const short8v*)&Kt[cur][(c * 16 + lr) * 72 + 32 + lg * 8];
        sacc[0][c] = MFMA_BF16(qf[0][0], kf0, sacc[0][c]);
        sacc[0][c] = MFMA_BF16(qf[0][1], kf1, sacc[0][c]);
        sacc[1][c] = MFMA_BF16(qf[1][0], kf0, sacc[1][c]);
        sacc[1][c] = MFMA_BF16(qf[1][1], kf1, sacc[1][c]);
      }
      // ---- online softmax ----
      const bool needmask = (kt >= 2 * qt);
      float xm[2][4] = {{-1e30f, -1e30f, -1e30f, -1e30f}, {-1e30f, -1e30f, -1e30f, -1e30f}};
#pragma unroll
      for (int m = 0; m < 2; ++m)
#pragma unroll
        for (int c = 0; c < 4; ++c) {
          f32x4 s = sacc[m][c];
#pragma unroll
          for (int r = 0; r < 4; ++r) {
            float v = s[r] * 0.125f;
            if (needmask) {
              const int kpos = kt * 64 + c * 16 + lr;
              const int qpos = qt * 128 + wave * 32 + m * 16 + lg * 4 + r;
              if (kpos > qpos) v = -1e30f;
            }
            s[r] = v;
            xm[m][r] = fmaxf(xm[m][r], v);
          }
          sacc[m][c] = s;
        }
#pragma unroll
      for (int mk = 1; mk <= 8; mk <<= 1)
#pragma unroll
        for (int m = 0; m < 2; ++m)
#pragma unroll
          for (int r = 0; r < 4; ++r) xm[m][r] = fmaxf(xm[m][r], __shfl_xor(xm[m][r], mk));
      float alpha[2][4];
#pragma unroll
      for (int m = 0; m < 2; ++m)
#pragma unroll
        for (int r = 0; r < 4; ++r) {
          const float mn = fmaxf(m_run[m][r], xm[m][r]);
          alpha[m][r] = __expf(m_run[m][r] - mn);
          m_run[m][r] = mn;
        }
      float rs[2][4] = {};
#pragma unroll
      for (int m = 0; m < 2; ++m)
#pragma unroll
        for (int c = 0; c < 4; ++c) {
          f32x4 s = sacc[m][c];
#pragma unroll
          for (int r = 0; r < 4; ++r) {
            const float e = __expf(s[r] - m_run[m][r]);
            s[r] = e;
            rs[m][r] += e;
          }
          sacc[m][c] = s;
        }
#pragma unroll
      for (int mk = 1; mk <= 8; mk <<= 1)
#pragma unroll
        for (int m = 0; m < 2; ++m)
#pragma unroll
          for (int r = 0; r < 4; ++r) rs[m][r] += __shfl_xor(rs[m][r], mk);
#pragma unroll
      for (int m = 0; m < 2; ++m)
#pragma unroll
        for (int r = 0; r < 4; ++r) l_run[m][r] = l_run[m][r] * alpha[m][r] + rs[m][r];
#pragma unroll
      for (int m = 0; m < 2; ++m)
#pragma unroll
        for (int n = 0; n < 4; ++n) {
          f32x4 t = oacc[m][n];
#pragma unroll
          for (int r = 0; r < 4; ++r) t[r] *= alpha[m][r];
          oacc[m][n] = t;
        }
      // ---- P -> LDS (wave-private), then O += P V ----
#pragma unroll
      for (int m = 0; m < 2; ++m)
#pragma unroll
        for (int c = 0; c < 4; ++c)
#pragma unroll
          for (int r = 0; r < 4; ++r)
            Pw[(m * 16 + lg * 4 + r) * 72 + c * 16 + lr] = f2bf(sacc[m][c][r]);
      short8v pa[2][2];
#pragma unroll
      for (int m = 0; m < 2; ++m) {
        pa[m][0] = *(const short8v*)&Pw[(m * 16 + lr) * 72 + lg * 8];
        pa[m][1] = *(const short8v*)&Pw[(m * 16 + lr) * 72 + 32 + lg * 8];
      }
#pragma unroll
      for (int n = 0; n < 4; ++n) {
        const short8v vf0 = *(const short8v*)&Vs[cur][(n * 16 + lr) * 72 + lg * 8];
        const short8v vf1 = *(const short8v*)&Vs[cur][(n * 16 + lr) * 72 + 32 + lg * 8];
        oacc[0][n] = MFMA_BF16(pa[0][0], vf0, oacc[0][n]);
        oacc[0][n] = MFMA_BF16(pa[0][1], vf1, oacc[0][n]);
        oacc[1][n] = MFMA_BF16(pa[1][0], vf0, oacc[1][n]);
        oacc[1][n] = MFMA_BF16(pa[1][1], vf1, oacc[1][n]);
      }
      // ---- stage next tile into other buffer ----
      if (more) {
        const int nxt = cur ^ 1;
        *(short8v*)&Kt[nxt][r_st * 72 + cb_st] = ka;
        *(short8v*)&Kt[nxt][r_st * 72 + cb_st + 8] = kb;
        *(short8v*)&Vs[nxt][r_st * 72 + cb_st] = va;
        *(short8v*)&Vs[nxt][r_st * 72 + cb_st + 8] = vb;
        cur = nxt;
      }
    }
    // ---- epilogue ----
#pragma unroll
    for (int m = 0; m < 2; ++m)
#pragma unroll
      for (int n = 0; n < 4; ++n)
#pragma unroll
        for (int r = 0; r < 4; ++r) {
          const int qpos = qt * 128 + wave * 32 + m * 16 + lg * 4 + r;
          O[(bbase + qpos) * 1024 + h * 64 + n * 16 + lr] =
              f2bf(oacc[m][n][r] / l_run[m][r]);
        }
  }
}

// ---------------------------------------------------------------------------
extern "C" void kernel_launch(void* const* d_in, const int* in_sizes, int n_in,
                              void* d_out, int out_size, void* d_ws, size_t ws_size,
                              hipStream_t stream) {
  (void)in_sizes; (void)n_in; (void)out_size; (void)ws_size;
  const float* x   = (const float*)d_in[0];
  const int* tpos  = (const int*)d_in[1];
  const float* Wq  = (const float*)d_in[2];
  const float* Wk  = (const float*)d_in[3];
  const float* Wv  = (const float*)d_in[4];
  const float* Wo  = (const float*)d_in[5];
  float* out = (float*)d_out;

  // workspace layout (72 MB total)
  char* ws = (char*)d_ws;
  u16* xb   = (u16*)(ws);                         // 16 MB; reused as attn_out
  u16* Wqkv = (u16*)(ws + (size_t)(16 << 20));    // 6 MB  ([3072][1024])
  u16* Wob  = (u16*)(ws + (size_t)(22 << 20));    // 2 MB
  u16* QKb  = (u16*)(ws + (size_t)(24 << 20));    // 32 MB ([8192][2048] Q|K)
  u16* Vtr  = (u16*)(ws + (size_t)(56 << 20));    // 16 MB ([b][h][64][2048])
  u16* Vtmp = (u16*)d_out;                        // scratch before final gemm

  cvt_f32_bf16<<<8192, 256, 0, stream>>>(x, xb, 8388608 / 4);
  cvt_f32_bf16<<<1024, 256, 0, stream>>>(Wq, Wqkv, 1048576 / 4);
  cvt_f32_bf16<<<1024, 256, 0, stream>>>(Wk, Wqkv + 1048576, 1048576 / 4);
  cvt_f32_bf16<<<1024, 256, 0, stream>>>(Wv, Wqkv + 2097152, 1048576 / 4);
  cvt_f32_bf16<<<1024, 256, 0, stream>>>(Wo, Wob, 1048576 / 4);

  // Q|K = xb @ Wqk^T ; Vtmp = xb @ Wv^T
  gemm_nt<true><<<dim3(16, 64), 256, 0, stream>>>(xb, Wqkv, QKb, 2048);
  gemm_nt<true><<<dim3(8, 64), 256, 0, stream>>>(xb, Wqkv + 2048 * 1024, Vtmp, 1024);

  rope_kernel<<<32768, 256, 0, stream>>>((u32*)QKb, tpos);
  transpose_v<<<dim3(32, 16, 4), 256, 0, stream>>>(Vtmp, Vtr);

  attn_kernel<<<512, 256, 0, stream>>>(QKb, Vtr, xb);

  // out = attn_out @ Wo^T  (fp32 epilogue)
  gemm_nt<false><<<dim3(8, 64), 256, 0, stream>>>(xb, Wob, out, 1024);
}

// Round 3
// 243.812 us; speedup vs baseline: 1.7199x; 1.1437x over previous
//
#include <hip/hip_runtime.h>
#include <cstdint>

using u16 = unsigned short;
using u32 = unsigned int;
using u64 = unsigned long long;

typedef __attribute__((ext_vector_type(8))) short short8v;   // 8 x bf16 (raw u16)
typedef __attribute__((ext_vector_type(4))) float f32x4;

#define MFMA_BF16(a, b, c) __builtin_amdgcn_mfma_f32_16x16x32_bf16((a), (b), (c), 0, 0, 0)

__device__ __forceinline__ u16 f2bf(float f) {
  u32 u = __float_as_uint(f);
  u += 0x7fffu + ((u >> 16) & 1u);   // RNE
  return (u16)(u >> 16);
}
__device__ __forceinline__ float bf2f(u32 s) { return __uint_as_float(s << 16); }
__device__ __forceinline__ u32 cvtpk(float a, float b) {
  u32 r;
  asm("v_cvt_pk_bf16_f32 %0, %1, %2" : "=v"(r) : "v"(a), "v"(b));
  return r;
}

__device__ __forceinline__ void g2l16(const u16* g, const u16* l) {
  __builtin_amdgcn_global_load_lds(
      (const __attribute__((address_space(1))) u32*)(uintptr_t)g,
      (__attribute__((address_space(3))) u32*)(u32)(uintptr_t)l, 16, 0, 0);
}

// ---------------- fp32 -> bf16 conversion ----------------
__global__ __launch_bounds__(256) void cvt_f32_bf16(const float* __restrict__ src,
                                                    u16* __restrict__ dst, int n4) {
  int i = blockIdx.x * blockDim.x + threadIdx.x;
  if (i >= n4) return;
  const float4 v = ((const float4*)src)[i];
  const u32 w0 = cvtpk(v.x, v.y), w1 = cvtpk(v.z, v.w);
  ((u64*)dst)[i] = (u64)w0 | ((u64)w1 << 32);
}

// ---------------- NT GEMM: C[M][N] = A[M][K] * B[N][K]^T, bf16 in, K=1024 ----
// MODE: 0 = fp32 out, 1 = bf16 out, 2 = bf16 transposed-V out ([b*1024+col][2048])
template <int MODE>
__global__ __launch_bounds__(256) void gemm_nt(const u16* __restrict__ A,
                                               const u16* __restrict__ B,
                                               void* __restrict__ C, int ldc) {
  constexpr int K = 1024;
  __shared__ u16 As[128 * 64];
  __shared__ u16 Bs[128 * 64];
  const int tid = threadIdx.x;
  const int lane = tid & 63, wave = tid >> 6;
  const int lr = lane & 15, lg = lane >> 4;
  const int bm = blockIdx.y * 128, bn = blockIdx.x * 128;
  const int wm = (wave >> 1) * 64, wn = (wave & 1) * 64;
  f32x4 acc[4][4] = {};
  for (int k0 = 0; k0 < K; k0 += 64) {
#pragma unroll
    for (int it = 0; it < 4; ++it) {
      const int ci = it * 4 + wave;
      const int li = ci * 512 + lane * 8;
      const int row = li >> 6, col = li & 63;
      g2l16(A + (size_t)(bm + row) * K + k0 + col, As + ci * 512);
      g2l16(B + (size_t)(bn + row) * K + k0 + col, Bs + ci * 512);
    }
    __syncthreads();
#pragma unroll
    for (int kk = 0; kk < 2; ++kk) {
      short8v af[4], bf[4];
#pragma unroll
      for (int m = 0; m < 4; ++m)
        af[m] = *(const short8v*)&As[(wm + m * 16 + lr) * 64 + kk * 32 + lg * 8];
#pragma unroll
      for (int n = 0; n < 4; ++n)
        bf[n] = *(const short8v*)&Bs[(wn + n * 16 + lr) * 64 + kk * 32 + lg * 8];
#pragma unroll
      for (int m = 0; m < 4; ++m)
#pragma unroll
        for (int n = 0; n < 4; ++n)
          acc[m][n] = MFMA_BF16(af[m], bf[n], acc[m][n]);
    }
    __syncthreads();
  }
#pragma unroll
  for (int m = 0; m < 4; ++m)
#pragma unroll
    for (int n = 0; n < 4; ++n) {
      if (MODE == 2) {
        const int col = bn + wn + n * 16 + lr;
        const int row0 = bm + wm + m * 16 + lg * 4;
        const int bb = row0 >> 11, sl = row0 & 2047;
        const u32 w0 = cvtpk(acc[m][n][0], acc[m][n][1]);
        const u32 w1 = cvtpk(acc[m][n][2], acc[m][n][3]);
        *(u64*)((u16*)C + ((size_t)(bb * 1024 + col)) * 2048 + sl) =
            (u64)w0 | ((u64)w1 << 32);
      } else {
#pragma unroll
        for (int r = 0; r < 4; ++r) {
          const int row = bm + wm + m * 16 + lg * 4 + r;
          const int col = bn + wn + n * 16 + lr;
          if (MODE == 1)
            ((u16*)C)[(size_t)row * ldc + col] = f2bf(acc[m][n][r]);
          else
            ((float*)C)[(size_t)row * ldc + col] = acc[m][n][r];
        }
      }
    }
}

// ---------------- RoPE in-place on QK buffer [8192][2048] -------------------
__global__ __launch_bounds__(256) void rope_kernel(u32* __restrict__ QKu,
                                                   const int* __restrict__ tpos) {
  const int t = blockIdx.x * 256 + threadIdx.x;   // 0 .. 8192*1024-1
  const int row = t >> 10, pp = t & 1023;
  const u32 u = QKu[t];
  const float e = bf2f(u & 0xffffu), o = bf2f(u >> 16);
  const int i = pp & 31;                          // pair index within head (dk=64)
  const float pos = (float)tpos[row & 2047];
  const float ang = pos * __expf((float)i * -0.28782313662425574f);
  float sn, cs;
  sincosf(ang, &sn, &cs);
  const float ne = e * cs - o * sn;
  const float no = o * cs + e * sn;
  QKu[t] = (u32)f2bf(ne) | ((u32)f2bf(no) << 16);
}

// ---------------- causal flash attention ------------------------------------
// 512 blocks; each handles q-tiles {15-p, p} (128 rows) for one (b,h).
// Swapped QK^T: mfma(K,Q) -> lane owns q = m*16+lr, kv = c*16+lg*4+r.
// P stays in registers (cvt_pk -> A-frags); V B-frags loaded with matching
// interleaved slot->kv map (consistent-permutation, correctness independent
// of the true HW k-slot mapping).
__global__ __launch_bounds__(256) void attn_kernel(const u16* __restrict__ QK,
                                                   const u16* __restrict__ Vt,
                                                   u16* __restrict__ O) {
  constexpr float SCALE = 0.18033688011112042f;   // 0.125 * log2(e); exp2 domain
  const int bid = blockIdx.x;
  const int hb = bid & 63, pr = bid >> 6;
  const int h = hb & 15, b = hb >> 4;
  const int tid = threadIdx.x, lane = tid & 63, wave = tid >> 6;
  const int lr = lane & 15, lg = lane >> 4;
  __shared__ u16 Kt[2][64 * 72];
  __shared__ u16 Vs[2][64 * 72];
  const size_t bbase = (size_t)b * 2048;
  const int r_st = tid >> 2, cb_st = (tid & 3) * 16;   // staging row/col
  const u16* Kbase = QK + (bbase + r_st) * 2048 + 1024 + h * 64 + cb_st;
  const u16* Vbase = Vt + ((size_t)(b * 16 + h) * 64 + r_st) * 2048 + cb_st;

  const int qts[2] = {15 - pr, pr};
  for (int qi = 0; qi < 2; ++qi) {
    const int qt = qts[qi];
    const int nkt = 2 * qt + 2;
    short8v qf[2][2];
#pragma unroll
    for (int m = 0; m < 2; ++m) {
      const u16* qp = QK + (bbase + qt * 128 + wave * 32 + m * 16 + lr) * 2048 + h * 64 + lg * 8;
      qf[m][0] = *(const short8v*)qp;
      qf[m][1] = *(const short8v*)(qp + 32);
    }
    f32x4 oacc[2][4] = {};
    float m_run[2] = {-1e30f, -1e30f}, l_run[2] = {0.f, 0.f};

    // prefetch tile 0
    short8v ka, kb, va, vb;
    ka = *(const short8v*)(Kbase);
    kb = *(const short8v*)(Kbase + 8);
    va = *(const short8v*)(Vbase);
    vb = *(const short8v*)(Vbase + 8);
    __syncthreads();   // previous q-tile's consumers done with LDS
    int cur = 0;
    *(short8v*)&Kt[0][r_st * 72 + cb_st] = ka;
    *(short8v*)&Kt[0][r_st * 72 + cb_st + 8] = kb;
    *(short8v*)&Vs[0][r_st * 72 + cb_st] = va;
    *(short8v*)&Vs[0][r_st * 72 + cb_st + 8] = vb;

    for (int kt = 0; kt < nkt; ++kt) {
      __syncthreads();   // buf[cur] visible
      const bool more = (kt + 1 < nkt);
      if (more) {
        const u16* kp = Kbase + (size_t)(kt + 1) * 64 * 2048;
        const u16* vp = Vbase + (kt + 1) * 64;
        ka = *(const short8v*)kp;
        kb = *(const short8v*)(kp + 8);
        va = *(const short8v*)vp;
        vb = *(const short8v*)(vp + 8);
      }
      // ---- S^T = K Q^T : lane owns q = m*16+lr, kv = c*16 + lg*4 + r ----
      f32x4 sacc[2][4] = {};
#pragma unroll
      for (int c = 0; c < 4; ++c) {
        const short8v kf0 = *(const short8v*)&Kt[cur][(c * 16 + lr) * 72 + lg * 8];
        const short8v kf1 = *(const short8v*)&Kt[cur][(c * 16 + lr) * 72 + 32 + lg * 8];
        sacc[0][c] = MFMA_BF16(kf0, qf[0][0], sacc[0][c]);
        sacc[0][c] = MFMA_BF16(kf1, qf[0][1], sacc[0][c]);
        sacc[1][c] = MFMA_BF16(kf0, qf[1][0], sacc[1][c]);
        sacc[1][c] = MFMA_BF16(kf1, qf[1][1], sacc[1][c]);
      }
      // ---- online softmax (exp2 domain), q lane-local ----
      const bool needmask = (kt >= 2 * qt);
      float xm[2] = {-1e30f, -1e30f};
#pragma unroll
      for (int m = 0; m < 2; ++m)
#pragma unroll
        for (int c = 0; c < 4; ++c) {
          f32x4 s = sacc[m][c];
#pragma unroll
          for (int r = 0; r < 4; ++r) {
            float v = s[r] * SCALE;
            if (needmask) {
              const int kpos = kt * 64 + c * 16 + lg * 4 + r;
              const int qpos = qt * 128 + wave * 32 + m * 16 + lr;
              if (kpos > qpos) v = -1e30f;
            }
            s[r] = v;
            xm[m] = fmaxf(xm[m], v);
          }
          sacc[m][c] = s;
        }
#pragma unroll
      for (int m = 0; m < 2; ++m) {
        xm[m] = fmaxf(xm[m], __shfl_xor(xm[m], 16));
        xm[m] = fmaxf(xm[m], __shfl_xor(xm[m], 32));
      }
      float alpha[2], rs[2] = {0.f, 0.f};
#pragma unroll
      for (int m = 0; m < 2; ++m) {
        const float mn = fmaxf(m_run[m], xm[m]);
        alpha[m] = exp2f(m_run[m] - mn);
        m_run[m] = mn;
      }
#pragma unroll
      for (int m = 0; m < 2; ++m)
#pragma unroll
        for (int c = 0; c < 4; ++c) {
          f32x4 s = sacc[m][c];
#pragma unroll
          for (int r = 0; r < 4; ++r) {
            const float e = exp2f(s[r] - m_run[m]);
            s[r] = e;
            rs[m] += e;
          }
          sacc[m][c] = s;
        }
#pragma unroll
      for (int m = 0; m < 2; ++m) {
        rs[m] += __shfl_xor(rs[m], 16);
        rs[m] += __shfl_xor(rs[m], 32);
        l_run[m] = l_run[m] * alpha[m] + rs[m];
      }
      // ---- rescale O (broadcast alpha from q=lr lanes to q=lg*4+r lanes) ----
#pragma unroll
      for (int m = 0; m < 2; ++m)
#pragma unroll
        for (int r = 0; r < 4; ++r) {
          const float ao = __shfl(alpha[m], lg * 4 + r);
#pragma unroll
          for (int n = 0; n < 4; ++n) oacc[m][n][r] *= ao;
        }
      // ---- pack P into A-frags in-register (slot j<4: c=2t, j>=4: c=2t+1) ----
      short8v pa[2][2];
#pragma unroll
      for (int m = 0; m < 2; ++m)
#pragma unroll
        for (int t = 0; t < 2; ++t) {
          union { short8v v; u32 w[4]; } P;
          P.w[0] = cvtpk(sacc[m][2 * t][0], sacc[m][2 * t][1]);
          P.w[1] = cvtpk(sacc[m][2 * t][2], sacc[m][2 * t][3]);
          P.w[2] = cvtpk(sacc[m][2 * t + 1][0], sacc[m][2 * t + 1][1]);
          P.w[3] = cvtpk(sacc[m][2 * t + 1][2], sacc[m][2 * t + 1][3]);
          pa[m][t] = P.v;
        }
      // ---- O += P V ; V B-frag slot j -> kv = 32t + 16*(j>>2) + 4lg + (j&3) ----
#pragma unroll
      for (int n = 0; n < 4; ++n) {
        const u16* vrow = &Vs[cur][(n * 16 + lr) * 72];
#pragma unroll
        for (int t = 0; t < 2; ++t) {
          union { short8v v; u64 d[2]; } V;
          V.d[0] = *(const u64*)(vrow + t * 32 + 4 * lg);
          V.d[1] = *(const u64*)(vrow + t * 32 + 16 + 4 * lg);
          oacc[0][n] = MFMA_BF16(pa[0][t], V.v, oacc[0][n]);
          oacc[1][n] = MFMA_BF16(pa[1][t], V.v, oacc[1][n]);
        }
      }
      // ---- stage next tile into other buffer ----
      if (more) {
        const int nxt = cur ^ 1;
        *(short8v*)&Kt[nxt][r_st * 72 + cb_st] = ka;
        *(short8v*)&Kt[nxt][r_st * 72 + cb_st + 8] = kb;
        *(short8v*)&Vs[nxt][r_st * 72 + cb_st] = va;
        *(short8v*)&Vs[nxt][r_st * 72 + cb_st + 8] = vb;
        cur = nxt;
      }
    }
    // ---- epilogue: O[q][d], q = qt*128+wave*32+m*16+lg*4+r, d = n*16+lr ----
#pragma unroll
    for (int m = 0; m < 2; ++m)
#pragma unroll
      for (int r = 0; r < 4; ++r) {
        const float linv = 1.0f / __shfl(l_run[m], lg * 4 + r);
        const int qpos = qt * 128 + wave * 32 + m * 16 + lg * 4 + r;
#pragma unroll
        for (int n = 0; n < 4; ++n)
          O[(bbase + qpos) * 1024 + h * 64 + n * 16 + lr] = f2bf(oacc[m][n][r] * linv);
      }
  }
}

// ---------------------------------------------------------------------------
extern "C" void kernel_launch(void* const* d_in, const int* in_sizes, int n_in,
                              void* d_out, int out_size, void* d_ws, size_t ws_size,
                              hipStream_t stream) {
  (void)in_sizes; (void)n_in; (void)out_size; (void)ws_size;
  const float* x   = (const float*)d_in[0];
  const int* tpos  = (const int*)d_in[1];
  const float* Wq  = (const float*)d_in[2];
  const float* Wk  = (const float*)d_in[3];
  const float* Wv  = (const float*)d_in[4];
  const float* Wo  = (const float*)d_in[5];
  float* out = (float*)d_out;

  // workspace layout (72 MB total)
  char* ws = (char*)d_ws;
  u16* xb   = (u16*)(ws);                         // 16 MB; reused as attn_out
  u16* Wqkv = (u16*)(ws + (size_t)(16 << 20));    // 6 MB  ([3072][1024])
  u16* Wob  = (u16*)(ws + (size_t)(22 << 20));    // 2 MB
  u16* QKb  = (u16*)(ws + (size_t)(24 << 20));    // 32 MB ([8192][2048] Q|K)
  u16* Vtr  = (u16*)(ws + (size_t)(56 << 20));    // 16 MB ([b][h][64][2048])

  cvt_f32_bf16<<<8192, 256, 0, stream>>>(x, xb, 8388608 / 4);
  cvt_f32_bf16<<<1024, 256, 0, stream>>>(Wq, Wqkv, 1048576 / 4);
  cvt_f32_bf16<<<1024, 256, 0, stream>>>(Wk, Wqkv + 1048576, 1048576 / 4);
  cvt_f32_bf16<<<1024, 256, 0, stream>>>(Wv, Wqkv + 2097152, 1048576 / 4);
  cvt_f32_bf16<<<1024, 256, 0, stream>>>(Wo, Wob, 1048576 / 4);

  // Q|K = xb @ Wqk^T ; Vtr = (xb @ Wv^T)^T  (transposed directly in epilogue)
  gemm_nt<1><<<dim3(16, 64), 256, 0, stream>>>(xb, Wqkv, QKb, 2048);
  gemm_nt<2><<<dim3(8, 64), 256, 0, stream>>>(xb, Wqkv + 2048 * 1024, Vtr, 0);

  rope_kernel<<<32768, 256, 0, stream>>>((u32*)QKb, tpos);

  attn_kernel<<<512, 256, 0, stream>>>(QKb, Vtr, xb);

  // out = attn_out @ Wo^T  (fp32 epilogue)
  gemm_nt<0><<<dim3(8, 64), 256, 0, stream>>>(xb, Wob, out, 1024);
}

// Round 4
// 223.585 us; speedup vs baseline: 1.8755x; 1.0905x over previous
//
#include <hip/hip_runtime.h>
#include <cstdint>

using u16 = unsigned short;
using u32 = unsigned int;
using u64 = unsigned long long;

typedef __attribute__((ext_vector_type(8))) short short8v;   // 8 x bf16 (raw u16)
typedef __attribute__((ext_vector_type(4))) float f32x4;

#define MFMA_BF16(a, b, c) __builtin_amdgcn_mfma_f32_16x16x32_bf16((a), (b), (c), 0, 0, 0)

__device__ __forceinline__ u16 f2bf(float f) {
  u32 u = __float_as_uint(f);
  u += 0x7fffu + ((u >> 16) & 1u);   // RNE
  return (u16)(u >> 16);
}
__device__ __forceinline__ float bf2f(u32 s) { return __uint_as_float(s << 16); }
__device__ __forceinline__ u32 cvtpk(float a, float b) {
  u32 r;
  asm("v_cvt_pk_bf16_f32 %0, %1, %2" : "=v"(r) : "v"(a), "v"(b));
  return r;
}

__device__ __forceinline__ void g2l16(const u16* g, const u16* l) {
  __builtin_amdgcn_global_load_lds(
      (const __attribute__((address_space(1))) u32*)(uintptr_t)g,
      (__attribute__((address_space(3))) u32*)(u32)(uintptr_t)l, 16, 0, 0);
}

// ---------------- fp32 -> bf16 conversion ----------------
__global__ __launch_bounds__(256) void cvt_f32_bf16(const float* __restrict__ src,
                                                    u16* __restrict__ dst, int n4) {
  int i = blockIdx.x * blockDim.x + threadIdx.x;
  if (i >= n4) return;
  const float4 v = ((const float4*)src)[i];
  const u32 w0 = cvtpk(v.x, v.y), w1 = cvtpk(v.z, v.w);
  ((u64*)dst)[i] = (u64)w0 | ((u64)w1 << 32);
}

// ---------------- NT GEMM: C[M][N] = A[M][K] * B[N][K]^T, bf16 in, K=1024 ----
// MODE: 0 = fp32 out, 1 = bf16 out, 2 = bf16 transposed-V out ([b*1024+col][2048])
// XCD-aware bijective swizzle (grid size must be a multiple of 8).
template <int MODE>
__global__ __launch_bounds__(256) void gemm_nt(const u16* __restrict__ A,
                                               const u16* __restrict__ B,
                                               void* __restrict__ C, int ldc) {
  constexpr int K = 1024;
  __shared__ u16 As[128 * 64];
  __shared__ u16 Bs[128 * 64];
  const int tid = threadIdx.x;
  const int lane = tid & 63, wave = tid >> 6;
  const int lr = lane & 15, lg = lane >> 4;
  const int nwg = gridDim.x * gridDim.y;
  int bid = blockIdx.y * gridDim.x + blockIdx.x;
  bid = (bid & 7) * (nwg >> 3) + (bid >> 3);
  const int bm = (bid / gridDim.x) * 128, bn = (bid % gridDim.x) * 128;
  const int wm = (wave >> 1) * 64, wn = (wave & 1) * 64;
  f32x4 acc[4][4] = {};
  for (int k0 = 0; k0 < K; k0 += 64) {
#pragma unroll
    for (int it = 0; it < 4; ++it) {
      const int ci = it * 4 + wave;
      const int li = ci * 512 + lane * 8;
      const int row = li >> 6, col = li & 63;
      g2l16(A + (size_t)(bm + row) * K + k0 + col, As + ci * 512);
      g2l16(B + (size_t)(bn + row) * K + k0 + col, Bs + ci * 512);
    }
    __syncthreads();
#pragma unroll
    for (int kk = 0; kk < 2; ++kk) {
      short8v af[4], bf[4];
#pragma unroll
      for (int m = 0; m < 4; ++m)
        af[m] = *(const short8v*)&As[(wm + m * 16 + lr) * 64 + kk * 32 + lg * 8];
#pragma unroll
      for (int n = 0; n < 4; ++n)
        bf[n] = *(const short8v*)&Bs[(wn + n * 16 + lr) * 64 + kk * 32 + lg * 8];
#pragma unroll
      for (int m = 0; m < 4; ++m)
#pragma unroll
        for (int n = 0; n < 4; ++n)
          acc[m][n] = MFMA_BF16(af[m], bf[n], acc[m][n]);
    }
    __syncthreads();
  }
#pragma unroll
  for (int m = 0; m < 4; ++m)
#pragma unroll
    for (int n = 0; n < 4; ++n) {
      if (MODE == 2) {
        const int col = bn + wn + n * 16 + lr;
        const int row0 = bm + wm + m * 16 + lg * 4;
        const int bb = row0 >> 11, sl = row0 & 2047;
        const u32 w0 = cvtpk(acc[m][n][0], acc[m][n][1]);
        const u32 w1 = cvtpk(acc[m][n][2], acc[m][n][3]);
        *(u64*)((u16*)C + ((size_t)(bb * 1024 + col)) * 2048 + sl) =
            (u64)w0 | ((u64)w1 << 32);
      } else {
#pragma unroll
        for (int r = 0; r < 4; ++r) {
          const int row = bm + wm + m * 16 + lg * 4 + r;
          const int col = bn + wn + n * 16 + lr;
          if (MODE == 1)
            ((u16*)C)[(size_t)row * ldc + col] = f2bf(acc[m][n][r]);
          else
            ((float*)C)[(size_t)row * ldc + col] = acc[m][n][r];
        }
      }
    }
}

// ---------------- RoPE in-place on QK buffer [8192][2048] -------------------
// Q half additionally scaled by 0.125*log2(e)  (attn softmax runs in exp2 domain)
__global__ __launch_bounds__(256) void rope_kernel(u32* __restrict__ QKu,
                                                   const int* __restrict__ tpos) {
  const int t = blockIdx.x * 256 + threadIdx.x;   // 0 .. 8192*1024-1
  const int row = t >> 10, pp = t & 1023;
  const u32 u = QKu[t];
  const float e = bf2f(u & 0xffffu), o = bf2f(u >> 16);
  const int i = pp & 31;                          // pair index within head (dk=64)
  const float pos = (float)tpos[row & 2047];
  const float ang = pos * __expf((float)i * -0.28782313662425574f);
  float sn, cs;
  sincosf(ang, &sn, &cs);
  const float sc = (pp < 512) ? 0.18033688011112042f : 1.0f;
  cs *= sc; sn *= sc;
  const float ne = e * cs - o * sn;
  const float no = o * cs + e * sn;
  QKu[t] = cvtpk(ne, no);
}

// ---------------- causal flash attention ------------------------------------
// 512 blocks x 512 threads (8 waves). Each block: q-tiles {15-p, p} (128 rows),
// each wave owns 16 q-rows. Swapped QK^T (mfma(K,Q)): lane owns q=lr,
// kv = c*16+lg*4+r; P stays in registers via cvt_pk; V B-frags use the matching
// slot->kv map. Defer-max (T13, THR=8 in exp2 domain). Double-buffered K/V LDS.
__global__ __launch_bounds__(512, 4) void attn_kernel(const u16* __restrict__ QK,
                                                      const u16* __restrict__ Vt,
                                                      u16* __restrict__ O) {
  const int bid = blockIdx.x;
  const int hb = bid & 63, pr = bid >> 6;          // pr in [0,8)
  const int h = hb & 15, b = hb >> 4;
  const int tid = threadIdx.x, lane = tid & 63, wave = tid >> 6;
  const int lr = lane & 15, lg = lane >> 4;
  __shared__ u16 Kt[2][64 * 72];
  __shared__ u16 Vs[2][64 * 72];
  const size_t bbase = (size_t)b * 2048;
  const int r_st = tid >> 3, cb_st = (tid & 7) * 8;   // staging: row, 8-u16 chunk
  const u16* Kbase = QK + (bbase + r_st) * 2048 + 1024 + h * 64 + cb_st;
  const u16* Vbase = Vt + ((size_t)(b * 16 + h) * 64 + r_st) * 2048 + cb_st;

  const int qts[2] = {15 - pr, pr};
  for (int qi = 0; qi < 2; ++qi) {
    const int qt = qts[qi];
    const int nkt = 2 * qt + 2;
    const int qrow = qt * 128 + wave * 16;           // wave's first q-row
    short8v qf0, qf1;
    {
      const u16* qp = QK + (bbase + qrow + lr) * 2048 + h * 64 + lg * 8;
      qf0 = *(const short8v*)qp;
      qf1 = *(const short8v*)(qp + 32);
    }
    f32x4 oacc[4] = {};
    float m_run = -1e30f, l_run = 0.f;

    // prefetch tile 0
    short8v ka = *(const short8v*)(Kbase);
    short8v va = *(const short8v*)(Vbase);
    __syncthreads();   // previous q-tile's consumers done with LDS
    int cur = 0;
    *(short8v*)&Kt[0][r_st * 72 + cb_st] = ka;
    *(short8v*)&Vs[0][r_st * 72 + cb_st] = va;

    for (int kt = 0; kt < nkt; ++kt) {
      __syncthreads();   // buf[cur] visible
      const bool more = (kt + 1 < nkt);
      if (more) {
        ka = *(const short8v*)(Kbase + (size_t)(kt + 1) * 64 * 2048);
        va = *(const short8v*)(Vbase + (kt + 1) * 64);
      }
      if (kt * 64 <= qrow + 15) {   // wave has at least one unmasked row
        // ---- S^T = K Q^T ----
        f32x4 sacc[4] = {};
#pragma unroll
        for (int c = 0; c < 4; ++c) {
          const short8v kf0 = *(const short8v*)&Kt[cur][(c * 16 + lr) * 72 + lg * 8];
          const short8v kf1 = *(const short8v*)&Kt[cur][(c * 16 + lr) * 72 + 32 + lg * 8];
          sacc[c] = MFMA_BF16(kf0, qf0, sacc[c]);
          sacc[c] = MFMA_BF16(kf1, qf1, sacc[c]);
        }
        // ---- online softmax (exp2 domain; scale pre-folded into Q) ----
        float xm = -1e30f;
        if (kt * 64 + 63 > qrow) {   // causal mask needed
          const int qpos = qrow + lr;
#pragma unroll
          for (int c = 0; c < 4; ++c) {
            f32x4 s = sacc[c];
#pragma unroll
            for (int r = 0; r < 4; ++r) {
              if (kt * 64 + c * 16 + lg * 4 + r > qpos) s[r] = -1e30f;
              xm = fmaxf(xm, s[r]);
            }
            sacc[c] = s;
          }
        } else {
#pragma unroll
          for (int c = 0; c < 4; ++c)
#pragma unroll
            for (int r = 0; r < 4; ++r) xm = fmaxf(xm, sacc[c][r]);
        }
        xm = fmaxf(xm, __shfl_xor(xm, 16));
        xm = fmaxf(xm, __shfl_xor(xm, 32));
        if (!__all(xm <= m_run + 8.0f)) {   // defer-max: rescale only on growth
          const float mn = fmaxf(m_run, xm);
          const float alpha = exp2f(m_run - mn);
          m_run = mn;
          l_run *= alpha;
#pragma unroll
          for (int r = 0; r < 4; ++r) {
            const float ao = __shfl(alpha, lg * 4 + r);
#pragma unroll
            for (int n = 0; n < 4; ++n) oacc[n][r] *= ao;
          }
        }
        float rs = 0.f;
#pragma unroll
        for (int c = 0; c < 4; ++c) {
          f32x4 s = sacc[c];
#pragma unroll
          for (int r = 0; r < 4; ++r) {
            const float e = exp2f(s[r] - m_run);
            s[r] = e;
            rs += e;
          }
          sacc[c] = s;
        }
        rs += __shfl_xor(rs, 16);
        rs += __shfl_xor(rs, 32);
        l_run += rs;
        // ---- pack P into A-frags (slot j<4: c=2t, j>=4: c=2t+1) ----
        short8v pa[2];
#pragma unroll
        for (int t = 0; t < 2; ++t) {
          union { short8v v; u32 w[4]; } P;
          P.w[0] = cvtpk(sacc[2 * t][0], sacc[2 * t][1]);
          P.w[1] = cvtpk(sacc[2 * t][2], sacc[2 * t][3]);
          P.w[2] = cvtpk(sacc[2 * t + 1][0], sacc[2 * t + 1][1]);
          P.w[3] = cvtpk(sacc[2 * t + 1][2], sacc[2 * t + 1][3]);
          pa[t] = P.v;
        }
        // ---- O += P V ; V slot j -> kv = 32t + 16*(j>>2) + 4lg + (j&3) ----
#pragma unroll
        for (int n = 0; n < 4; ++n) {
          const u16* vrow = &Vs[cur][(n * 16 + lr) * 72];
#pragma unroll
          for (int t = 0; t < 2; ++t) {
            union { short8v v; u64 d[2]; } V;
            V.d[0] = *(const u64*)(vrow + t * 32 + 4 * lg);
            V.d[1] = *(const u64*)(vrow + t * 32 + 16 + 4 * lg);
            oacc[n] = MFMA_BF16(pa[t], V.v, oacc[n]);
          }
        }
      }
      // ---- stage next tile into other buffer ----
      if (more) {
        const int nxt = cur ^ 1;
        *(short8v*)&Kt[nxt][r_st * 72 + cb_st] = ka;
        *(short8v*)&Vs[nxt][r_st * 72 + cb_st] = va;
        cur = nxt;
      }
    }
    // ---- epilogue: O[q][d], q = qrow + lg*4 + r, d = n*16 + lr ----
#pragma unroll
    for (int r = 0; r < 4; ++r) {
      const float linv = 1.0f / __shfl(l_run, lg * 4 + r);
      const int qpos = qrow + lg * 4 + r;
#pragma unroll
      for (int n = 0; n < 4; ++n)
        O[(bbase + qpos) * 1024 + h * 64 + n * 16 + lr] = f2bf(oacc[n][r] * linv);
    }
  }
}

// ---------------------------------------------------------------------------
extern "C" void kernel_launch(void* const* d_in, const int* in_sizes, int n_in,
                              void* d_out, int out_size, void* d_ws, size_t ws_size,
                              hipStream_t stream) {
  (void)in_sizes; (void)n_in; (void)out_size; (void)ws_size;
  const float* x   = (const float*)d_in[0];
  const int* tpos  = (const int*)d_in[1];
  const float* Wq  = (const float*)d_in[2];
  const float* Wk  = (const float*)d_in[3];
  const float* Wv  = (const float*)d_in[4];
  const float* Wo  = (const float*)d_in[5];
  float* out = (float*)d_out;

  // workspace layout (72 MB total)
  char* ws = (char*)d_ws;
  u16* xb   = (u16*)(ws);                         // 16 MB; reused as attn_out
  u16* Wqkv = (u16*)(ws + (size_t)(16 << 20));    // 6 MB  ([3072][1024])
  u16* Wob  = (u16*)(ws + (size_t)(22 << 20));    // 2 MB
  u16* QKb  = (u16*)(ws + (size_t)(24 << 20));    // 32 MB ([8192][2048] Q|K)
  u16* Vtr  = (u16*)(ws + (size_t)(56 << 20));    // 16 MB ([b][h][64][2048])

  cvt_f32_bf16<<<8192, 256, 0, stream>>>(x, xb, 8388608 / 4);
  cvt_f32_bf16<<<1024, 256, 0, stream>>>(Wq, Wqkv, 1048576 / 4);
  cvt_f32_bf16<<<1024, 256, 0, stream>>>(Wk, Wqkv + 1048576, 1048576 / 4);
  cvt_f32_bf16<<<1024, 256, 0, stream>>>(Wv, Wqkv + 2097152, 1048576 / 4);
  cvt_f32_bf16<<<1024, 256, 0, stream>>>(Wo, Wob, 1048576 / 4);

  // Q|K = xb @ Wqk^T ; Vtr = (xb @ Wv^T)^T  (transposed directly in epilogue)
  gemm_nt<1><<<dim3(16, 64), 256, 0, stream>>>(xb, Wqkv, QKb, 2048);
  gemm_nt<2><<<dim3(8, 64), 256, 0, stream>>>(xb, Wqkv + 2048 * 1024, Vtr, 0);

  rope_kernel<<<32768, 256, 0, stream>>>((u32*)QKb, tpos);

  attn_kernel<<<512, 512, 0, stream>>>(QKb, Vtr, xb);

  // out = attn_out @ Wo^T  (fp32 epilogue)
  gemm_nt<0><<<dim3(8, 64), 256, 0, stream>>>(xb, Wob, out, 1024);
}